// Round 11
// baseline (82.574 us; speedup 1.0000x reference)
//
#include <hip/hip_runtime.h>

// ============================ R11: DIAGNOSTIC BUILD ==========================
// R10's kernel with the GEMM K-pass repeated 4x (REPS). Output is identical
// (acc zeroed per rep; partial overwritten each rep - stores keep reps live,
// no DCE). Purpose: push k_gemm above the harness fillBuffer dispatches
// (40-44us) so its rocprof counters finally appear in top-5, and recover
// gemm_time = (dur_R11 - dur_R10) / 3 to separate node-overhead from work.
// ============================================================================

#define BATCH 512
#define INFEAT 4096
#define LOUT 1023
#define NCLS 1000
#define NPAD 1024
#define SPLITK 8
#define REPS 4      // diagnostic multiplier

typedef __bf16 bf16x8 __attribute__((ext_vector_type(8)));
typedef float f32x4 __attribute__((ext_vector_type(4)));

__device__ __forceinline__ unsigned short f2bf(float a) {
    unsigned u = __builtin_bit_cast(unsigned, a);
    return (unsigned short)((u + 0x7fffu + ((u >> 16) & 1u)) >> 16);
}
__device__ __forceinline__ float bf2f(unsigned short u) {
    return __builtin_bit_cast(float, ((unsigned)u) << 16);
}
__device__ __forceinline__ uint4 pack8(float4 a, float4 b) {
    union { __bf16 h[8]; uint4 u; } r;
    r.h[0] = (__bf16)a.x; r.h[1] = (__bf16)a.y;
    r.h[2] = (__bf16)a.z; r.h[3] = (__bf16)a.w;
    r.h[4] = (__bf16)b.x; r.h[5] = (__bf16)b.y;
    r.h[6] = (__bf16)b.z; r.h[7] = (__bf16)b.w;
    return r.u;
}

__global__ __launch_bounds__(256, 4) void k_gemm(
    const float* __restrict__ x, const float* __restrict__ W,
    unsigned short* __restrict__ partial) {
    __shared__ unsigned char lds[32768];      // 2 x (8KB A + 8KB B)
    const int bid = blockIdx.x;
    const int work = (bid & 7) * 128 + (bid >> 3);  // chunked XCD swizzle
    const int bn = work & 15, bm = (work >> 4) & 7, sp = work >> 7;
    const int tid = threadIdx.x;
    const int wave = tid >> 6, lane = tid & 63;
    const int lrow = lane & 15, lgrp = lane >> 4;
    const int wr = wave >> 1, wc = wave & 1;        // 2 x 2 wave grid
    const int arow0 = bm * 64, brow0 = bn * 64, chunk0 = sp * 8;

    const int row0 = tid >> 3, jb0 = tid & 7;        // rows 0..31
    const int row1 = 32 + (tid >> 3), jb1 = tid & 7; // rows 32..63

    float4 sa[4], sb[4];

    auto LOADR = [&](int t) {
        const size_t c0 = (size_t)(chunk0 + t) * 64;
        {
            const float4* q = (const float4*)(x + (size_t)(arow0 + row0) * INFEAT + c0 + jb0 * 8);
            sa[0] = q[0]; sa[1] = q[1];
        }
        {
            const float4* q = (const float4*)(x + (size_t)(arow0 + row1) * INFEAT + c0 + jb1 * 8);
            sa[2] = q[0]; sa[3] = q[1];
        }
        {
            int wrow = brow0 + row0;
            if (wrow < LOUT) {
                const float4* q = (const float4*)(W + (size_t)wrow * INFEAT + c0 + jb0 * 8);
                sb[0] = q[0]; sb[1] = q[1];
            } else {
                sb[0] = make_float4(0.f, 0.f, 0.f, 0.f);
                sb[1] = make_float4(0.f, 0.f, 0.f, 0.f);
            }
        }
        {
            int wrow = brow0 + row1;
            if (wrow < LOUT) {
                const float4* q = (const float4*)(W + (size_t)wrow * INFEAT + c0 + jb1 * 8);
                sb[2] = q[0]; sb[3] = q[1];
            } else {
                sb[2] = make_float4(0.f, 0.f, 0.f, 0.f);
                sb[3] = make_float4(0.f, 0.f, 0.f, 0.f);
            }
        }
    };

    auto WRITE = [&](int bsel) {
        unsigned char* lA = lds + bsel * 16384;
        unsigned char* lB = lA + 8192;
        *(uint4*)(lA + row0 * 128 + ((jb0 ^ (row0 & 7)) * 16)) = pack8(sa[0], sa[1]);
        *(uint4*)(lA + row1 * 128 + ((jb1 ^ (row1 & 7)) * 16)) = pack8(sa[2], sa[3]);
        *(uint4*)(lB + row0 * 128 + ((jb0 ^ (row0 & 7)) * 16)) = pack8(sb[0], sb[1]);
        *(uint4*)(lB + row1 * 128 + ((jb1 ^ (row1 & 7)) * 16)) = pack8(sb[2], sb[3]);
    };

    unsigned short* P = partial + (size_t)sp * (BATCH * NPAD);

#pragma unroll 1
    for (int rep = 0; rep < REPS; ++rep) {
        f32x4 acc[2][2] = {};

        LOADR(0);
        WRITE(0);
        LOADR(1);
        __syncthreads();

#pragma unroll 1
        for (int t = 0; t < 8; ++t) {
            const int cur = t & 1;
            const unsigned char* lA = lds + cur * 16384;
            const unsigned char* lB = lA + 8192;
            bf16x8 fa[2][2], fb[2][2];
#pragma unroll
            for (int ks = 0; ks < 2; ++ks) {
                int swz = ((ks * 4 + lgrp) ^ (lrow & 7)) * 16;
#pragma unroll
                for (int m = 0; m < 2; ++m)
                    fa[ks][m] = *(const bf16x8*)(lA + (wr * 32 + m * 16 + lrow) * 128 + swz);
#pragma unroll
                for (int n = 0; n < 2; ++n)
                    fb[ks][n] = *(const bf16x8*)(lB + (wc * 32 + n * 16 + lrow) * 128 + swz);
            }
            __builtin_amdgcn_s_setprio(1);
#pragma unroll
            for (int ks = 0; ks < 2; ++ks)
#pragma unroll
                for (int m = 0; m < 2; ++m)
#pragma unroll
                    for (int n = 0; n < 2; ++n)
                        acc[m][n] = __builtin_amdgcn_mfma_f32_16x16x32_bf16(
                            fa[ks][m], fb[ks][n], acc[m][n], 0, 0, 0);
            __builtin_amdgcn_s_setprio(0);
            if (t + 1 < 8) {
                WRITE(cur ^ 1);
                if (t + 2 < 8) LOADR(t + 2);
            }
            asm volatile("s_waitcnt lgkmcnt(0)" ::: "memory");
            __builtin_amdgcn_s_barrier();
        }

        // store each rep (side effect keeps every rep live; same final bytes)
#pragma unroll
        for (int m = 0; m < 2; ++m)
#pragma unroll
            for (int n = 0; n < 2; ++n)
#pragma unroll
                for (int reg = 0; reg < 4; ++reg) {
                    int r = arow0 + wr * 32 + m * 16 + lgrp * 4 + reg;
                    int c = brow0 + wc * 32 + n * 16 + lrow;
                    P[(size_t)r * NPAD + c] = f2bf(acc[m][n][reg]);
                }
        __syncthreads();   // stores done before next rep re-stages LDS
    }
}

// ---------------- fused: split-K reduce + bias + tanh + FWHT + inv + norm ----
__global__ __launch_bounds__(256) void k_fused(const unsigned short* __restrict__ partial,
                                               const float* __restrict__ bias,
                                               const float* __restrict__ epsp,
                                               const float* __restrict__ powp,
                                               float* __restrict__ out) {
    __shared__ float g[1024];
    __shared__ float wsum[4];
    const int r = blockIdx.x, t = threadIdx.x;
    const int n0 = t * 4;

    f32x4 v = {0.0f, 0.0f, 0.0f, 0.0f};
#pragma unroll
    for (int s = 0; s < SPLITK; ++s) {
        ushort4 p = *(const ushort4*)(partial + ((size_t)s * BATCH + r) * NPAD + n0);
        v[0] += bf2f(p.x); v[1] += bf2f(p.y); v[2] += bf2f(p.z); v[3] += bf2f(p.w);
    }
    float bb[4];
    if (t < 255) {
        float4 b4 = *(const float4*)(bias + n0);
        bb[0] = b4.x; bb[1] = b4.y; bb[2] = b4.z; bb[3] = b4.w;
    } else {
        bb[0] = bias[1020]; bb[1] = bias[1021]; bb[2] = bias[1022]; bb[3] = 0.0f;
    }
    if (t == 0) g[0] = 0.0f;
#pragma unroll
    for (int j = 0; j < 4; ++j) {
        int n = n0 + j;
        if (n < LOUT) g[n + 1] = tanhf(v[j] + bb[j]);
    }
    __syncthreads();

#pragma unroll 1
    for (int s = 0; s < 10; ++s) {
        int st = 1 << s;
#pragma unroll
        for (int pp = 0; pp < 2; ++pp) {
            int p = t + pp * 256;
            int idx = ((p >> s) << (s + 1)) | (p & (st - 1));
            float a = g[idx], c = g[idx + st];
            g[idx] = a + c;
            g[idx + st] = a - c;
        }
        __syncthreads();
    }

    const float eps = *epsp, pw = *powp;
    float iv[4];
    float ss = 0.0f;
#pragma unroll
    for (int j = 0; j < 4; ++j) {
        int c = n0 + j;
        float d = fmaxf(1023.0f - g[c], eps);
        float q = (pw == 1.0f) ? (1.0f / d) : powf(d, -pw);
        if (c >= NCLS) q = 0.0f;
        iv[j] = q;
        ss += q;
    }
#pragma unroll
    for (int m = 32; m; m >>= 1) ss += __shfl_xor(ss, m, 64);
    if ((t & 63) == 0) wsum[t >> 6] = ss;
    __syncthreads();
    float sc = 1.0f / (wsum[0] + wsum[1] + wsum[2] + wsum[3]);

    if (n0 < NCLS) {
        float4 o;
        o.x = iv[0] * sc; o.y = iv[1] * sc; o.z = iv[2] * sc; o.w = iv[3] * sc;
        *(float4*)(out + (size_t)r * NCLS + n0) = o;
    }
}

extern "C" void kernel_launch(void* const* d_in, const int* in_sizes, int n_in,
                              void* d_out, int out_size, void* d_ws, size_t ws_size,
                              hipStream_t stream) {
    const float* x = (const float*)d_in[0];       // (512, 4096)
    const float* W = (const float*)d_in[1];       // (1023, 4096)
    const float* b = (const float*)d_in[2];       // (1023,)
    // d_in[3] = labels: NOT needed (Hadamard structure -> FWHT)
    const float* epsp = (const float*)d_in[4];
    const float* powp = (const float*)d_in[5];
    float* out = (float*)d_out;                   // (512, 1000)

    unsigned char* ws = (unsigned char*)d_ws;
    unsigned short* partial = (unsigned short*)ws;  // 8 MB (8 x 512 x 1024 bf16)

    k_gemm<<<1024, 256, 0, stream>>>(x, W, partial);
    k_fused<<<512, 256, 0, stream>>>(partial, b, epsp, powp, out);
}

// Round 12
// 27.380 us; speedup vs baseline: 3.0158x; 3.0158x over previous
//
#include <hip/hip_runtime.h>

// Problem constants
#define BATCH 512
#define INFEAT 4096
#define LOUT 1023   // code_length - 1
#define NCLS 1000
#define NPAD 1024
#define SPLITK 8

typedef __bf16 bf16x8 __attribute__((ext_vector_type(8)));
typedef float f32x4 __attribute__((ext_vector_type(4)));

__device__ __forceinline__ unsigned short f2bf(float a) {
    unsigned u = __builtin_bit_cast(unsigned, a);
    return (unsigned short)((u + 0x7fffu + ((u >> 16) & 1u)) >> 16);
}
__device__ __forceinline__ unsigned f2bf2(float a, float b) {
    return (unsigned)f2bf(a) | ((unsigned)f2bf(b) << 16);
}
__device__ __forceinline__ float bf2f(unsigned short u) {
    return __builtin_bit_cast(float, ((unsigned)u) << 16);
}

__device__ __forceinline__ void gload_lds16(const void* g, void* l) {
    __builtin_amdgcn_global_load_lds(
        (const __attribute__((address_space(1))) void*)g,
        (__attribute__((address_space(3))) void*)l, 16, 0, 0);
}

// ---------------- convert: x and W -> pre-swizzled bf16 (R2 scheme) ----------
// Row-major, row stride 8192B. Within each 128B (64-elem) K-chunk, the 16B
// granule at slot s holds logical granule s^(row&7) — the inverse of the XOR
// applied at ds_read time, so global->LDS staging is a LINEAR glds copy.
// This kernel is at its BW floor (~38 MB total traffic ≈ 6 us).
__global__ __launch_bounds__(256) void k_cvt(const float* __restrict__ x,
                                             const float* __restrict__ W,
                                             unsigned char* __restrict__ xb,
                                             unsigned char* __restrict__ Wb) {
    int blk = blockIdx.x;
    if (blk < 1024) {                          // x: 512 rows x 512 granules
        int g = blk * 256 + threadIdx.x;
        int r = g >> 9, k16 = g & 511;
        const float4* p = (const float4*)(x + (size_t)r * INFEAT + k16 * 8);
        float4 v0 = p[0], v1 = p[1];
        uint4 o;
        o.x = f2bf2(v0.x, v0.y); o.y = f2bf2(v0.z, v0.w);
        o.z = f2bf2(v1.x, v1.y); o.w = f2bf2(v1.z, v1.w);
        *(uint4*)(xb + (size_t)r * 8192 + (k16 >> 3) * 128 + (((k16 & 7) ^ (r & 7)) * 16)) = o;
    } else {                                    // W: 1024 rows x 512 granules
        int g = (blk - 1024) * 256 + threadIdx.x;
        int r = g >> 9, k16 = g & 511;
        uint4 o = {0, 0, 0, 0};
        if (r < LOUT) {
            const float4* p = (const float4*)(W + (size_t)r * INFEAT + k16 * 8);
            float4 v0 = p[0], v1 = p[1];
            o.x = f2bf2(v0.x, v0.y); o.y = f2bf2(v0.z, v0.w);
            o.z = f2bf2(v1.x, v1.y); o.w = f2bf2(v1.z, v1.w);
        }
        *(uint4*)(Wb + (size_t)r * 8192 + (k16 >> 3) * 128 + (((k16 & 7) ^ (r & 7)) * 16)) = o;
    }
}

// ---------------- GEMM: partial[s] = xb @ Wb^T (split-K, glds staging) -------
// LEAN-LOOP design from R11's counters (nothing saturated; reg-staging chain
// was the cost). BM=BN=64, BK=64, SK=8 -> 1024 blocks = 5 blocks/CU
// co-resident (LDS 32KB dbuf, launch_bounds(256,5) -> 20 waves/CU). Per
// thread-step: 4 global_load_lds + 8 ds_read_b128 + 16 MFMA — no cvt, no
// ds_write, no reg round-trip. Classic 2-phase loop (stage-next, compute,
// vmcnt(0)+barrier); the stall is hidden by the 4 other resident blocks
// (m114), not by intra-block pipelining. Chunked XCD swizzle: 128
// consecutive works = one sp-slice/XCD (1.5 MB bf16, L2-resident).
__global__ __launch_bounds__(256, 5) void k_gemm(
    const unsigned char* __restrict__ xb, const unsigned char* __restrict__ Wb,
    unsigned short* __restrict__ partial) {
    __shared__ unsigned char lds[32768];      // 2 x (8KB A + 8KB B)
    const int bid = blockIdx.x;
    const int work = (bid & 7) * 128 + (bid >> 3);  // chunked XCD swizzle
    const int bn = work & 15, bm = (work >> 4) & 7, sp = work >> 7;
    const int tid = threadIdx.x;
    const int wave = tid >> 6, lane = tid & 63;
    const int lrow = lane & 15, lgrp = lane >> 4;
    const int wr = wave >> 1, wc = wave & 1;        // 2 x 2 wave grid
    const int arow0 = bm * 64, brow0 = bn * 64, chunk0 = sp * 8;

    // staging: two 1KB segments per wave for A, two for B (linear glds dest)
    const int g0 = wave * 2 * 64 + lane;            // granule ids
    const int g1 = (wave * 2 + 1) * 64 + lane;
    const int r0 = g0 >> 3, s0 = g0 & 7;
    const int r1 = g1 >> 3, s1 = g1 & 7;

    f32x4 acc[2][2] = {};

    auto STAGE = [&](int bsel, int c) {
        unsigned char* lA = lds + bsel * 16384;
        unsigned char* lB = lA + 8192;
        gload_lds16(xb + (size_t)(arow0 + r0) * 8192 + c * 128 + s0 * 16,
                    lA + wave * 2048);
        gload_lds16(xb + (size_t)(arow0 + r1) * 8192 + c * 128 + s1 * 16,
                    lA + wave * 2048 + 1024);
        gload_lds16(Wb + (size_t)(brow0 + r0) * 8192 + c * 128 + s0 * 16,
                    lB + wave * 2048);
        gload_lds16(Wb + (size_t)(brow0 + r1) * 8192 + c * 128 + s1 * 16,
                    lB + wave * 2048 + 1024);
    };

    auto COMPUTE = [&](int bsel) {
        const unsigned char* lA = lds + bsel * 16384;
        const unsigned char* lB = lA + 8192;
        bf16x8 fa[2][2], fb[2][2];
#pragma unroll
        for (int ks = 0; ks < 2; ++ks) {
            int swz = ((ks * 4 + lgrp) ^ (lrow & 7)) * 16;
#pragma unroll
            for (int m = 0; m < 2; ++m)
                fa[ks][m] = *(const bf16x8*)(lA + (wr * 32 + m * 16 + lrow) * 128 + swz);
#pragma unroll
            for (int n = 0; n < 2; ++n)
                fb[ks][n] = *(const bf16x8*)(lB + (wc * 32 + n * 16 + lrow) * 128 + swz);
        }
        __builtin_amdgcn_s_setprio(1);
#pragma unroll
        for (int ks = 0; ks < 2; ++ks)
#pragma unroll
            for (int m = 0; m < 2; ++m)
#pragma unroll
                for (int n = 0; n < 2; ++n)
                    acc[m][n] = __builtin_amdgcn_mfma_f32_16x16x32_bf16(
                        fa[ks][m], fb[ks][n], acc[m][n], 0, 0, 0);
        __builtin_amdgcn_s_setprio(0);
    };

    // --- classic 2-phase loop (T3-minimum recipe) ---
    STAGE(0, chunk0);
    asm volatile("s_waitcnt vmcnt(0)" ::: "memory");
    __builtin_amdgcn_s_barrier();
#pragma unroll 1
    for (int t = 0; t < 8; ++t) {
        const int cur = t & 1;
        if (t + 1 < 8) STAGE(cur ^ 1, chunk0 + t + 1);
        COMPUTE(cur);
        asm volatile("s_waitcnt vmcnt(0) lgkmcnt(0)" ::: "memory");
        __builtin_amdgcn_s_barrier();
    }

    // --- epilogue: bf16 partials ---
    unsigned short* P = partial + (size_t)sp * (BATCH * NPAD);
#pragma unroll
    for (int m = 0; m < 2; ++m)
#pragma unroll
        for (int n = 0; n < 2; ++n)
#pragma unroll
            for (int reg = 0; reg < 4; ++reg) {
                int r = arow0 + wr * 32 + m * 16 + lgrp * 4 + reg;
                int c = brow0 + wc * 32 + n * 16 + lrow;
                P[(size_t)r * NPAD + c] = f2bf(acc[m][n][reg]);
            }
}

// ---------------- fused: split-K reduce + bias + tanh + FWHT + inv + norm ----
// One block per batch row. dot[c] = sum_j h[j]*H[c][j+1] = FWHT(g)[c] with
// g[0]=0, g[k]=h[k-1]  (Sylvester H symmetric; H[c][0]*g[0]=0 drops out).
__global__ __launch_bounds__(256) void k_fused(const unsigned short* __restrict__ partial,
                                               const float* __restrict__ bias,
                                               const float* __restrict__ epsp,
                                               const float* __restrict__ powp,
                                               float* __restrict__ out) {
    __shared__ float g[1024];
    __shared__ float wsum[4];
    const int r = blockIdx.x, t = threadIdx.x;
    const int n0 = t * 4;

    f32x4 v = {0.0f, 0.0f, 0.0f, 0.0f};
#pragma unroll
    for (int s = 0; s < SPLITK; ++s) {
        ushort4 p = *(const ushort4*)(partial + ((size_t)s * BATCH + r) * NPAD + n0);
        v[0] += bf2f(p.x); v[1] += bf2f(p.y); v[2] += bf2f(p.z); v[3] += bf2f(p.w);
    }
    float bb[4];
    if (t < 255) {
        float4 b4 = *(const float4*)(bias + n0);
        bb[0] = b4.x; bb[1] = b4.y; bb[2] = b4.z; bb[3] = b4.w;
    } else {
        bb[0] = bias[1020]; bb[1] = bias[1021]; bb[2] = bias[1022]; bb[3] = 0.0f;
    }
    if (t == 0) g[0] = 0.0f;
#pragma unroll
    for (int j = 0; j < 4; ++j) {
        int n = n0 + j;
        if (n < LOUT) g[n + 1] = tanhf(v[j] + bb[j]);
    }
    __syncthreads();

    // FWHT: 10 stages, 512 butterflies/stage, 2 per thread
#pragma unroll 1
    for (int s = 0; s < 10; ++s) {
        int st = 1 << s;
#pragma unroll
        for (int pp = 0; pp < 2; ++pp) {
            int p = t + pp * 256;
            int idx = ((p >> s) << (s + 1)) | (p & (st - 1));
            float a = g[idx], c = g[idx + st];
            g[idx] = a + c;
            g[idx + st] = a - c;
        }
        __syncthreads();
    }

    const float eps = *epsp, pw = *powp;
    float iv[4];
    float ss = 0.0f;
#pragma unroll
    for (int j = 0; j < 4; ++j) {
        int c = n0 + j;
        float d = fmaxf(1023.0f - g[c], eps);
        float q = (pw == 1.0f) ? (1.0f / d) : powf(d, -pw);
        if (c >= NCLS) q = 0.0f;
        iv[j] = q;
        ss += q;
    }
#pragma unroll
    for (int m = 32; m; m >>= 1) ss += __shfl_xor(ss, m, 64);
    if ((t & 63) == 0) wsum[t >> 6] = ss;
    __syncthreads();
    float sc = 1.0f / (wsum[0] + wsum[1] + wsum[2] + wsum[3]);

    if (n0 < NCLS) {  // NCLS = 1000 = 4*250: threads 0..249 store full float4
        float4 o;
        o.x = iv[0] * sc; o.y = iv[1] * sc; o.z = iv[2] * sc; o.w = iv[3] * sc;
        *(float4*)(out + (size_t)r * NCLS + n0) = o;
    }
}

extern "C" void kernel_launch(void* const* d_in, const int* in_sizes, int n_in,
                              void* d_out, int out_size, void* d_ws, size_t ws_size,
                              hipStream_t stream) {
    const float* x = (const float*)d_in[0];       // (512, 4096)
    const float* W = (const float*)d_in[1];       // (1023, 4096)
    const float* b = (const float*)d_in[2];       // (1023,)
    // d_in[3] = labels: NOT needed (Hadamard structure -> FWHT)
    const float* epsp = (const float*)d_in[4];
    const float* powp = (const float*)d_in[5];
    float* out = (float*)d_out;                   // (512, 1000)

    unsigned char* ws = (unsigned char*)d_ws;
    unsigned char* xb = ws;                          // 4 MB (512 x 4096 bf16, swz)
    unsigned char* Wb = ws + (4u << 20);             // 8 MB (1024 x 4096 bf16, swz)
    unsigned short* partial = (unsigned short*)(ws + (12u << 20));  // 8 MB

    k_cvt<<<3072, 256, 0, stream>>>(x, W, xb, Wb);
    k_gemm<<<1024, 256, 0, stream>>>(xb, Wb, partial);
    k_fused<<<512, 256, 0, stream>>>(partial, b, epsp, powp, out);
}